// Round 1
// baseline (1345.411 us; speedup 1.0000x reference)
//
#include <hip/hip_runtime.h>

#define NN 50000
#define NE 500000
#define NGR 64
#define HD 128
#define INF 5
#define BN_EPS 1e-5f

// ---------- graph norm ----------
__global__ void k_init_deg(float* deg) {
    int i = blockIdx.x * 256 + threadIdx.x;
    if (i < NN) deg[i] = 1.0f;  // self-loop weight
}

__global__ void k_deg_edges(const int* __restrict__ ei, const float* __restrict__ ea,
                            float* __restrict__ deg) {
    int e = blockIdx.x * 256 + threadIdx.x;
    if (e < NE) atomicAdd(&deg[ei[NE + e]], ea[e]);  // col = ei[1]
}

__global__ void k_dinv(float* deg) {
    int i = blockIdx.x * 256 + threadIdx.x;
    if (i < NN) {
        float d = deg[i];
        deg[i] = d > 0.f ? rsqrtf(d) : 0.f;
    }
}

// ---------- CSR build (by destination/col) ----------
__global__ void k_hist(const int* __restrict__ ei, int* __restrict__ cnt) {
    int e = blockIdx.x * 256 + threadIdx.x;
    if (e < NE) atomicAdd(&cnt[ei[NE + e]], 1);
}

__global__ void k_scan(const int* __restrict__ cnt, int* __restrict__ col_ptr) {
    __shared__ int sm[1024];
    __shared__ int carry;
    if (threadIdx.x == 0) carry = 0;
    __syncthreads();
    for (int base = 0; base < NN; base += 1024) {
        int i = base + threadIdx.x;
        int v = (i < NN) ? cnt[i] : 0;
        sm[threadIdx.x] = v;
        __syncthreads();
        for (int off = 1; off < 1024; off <<= 1) {
            int t = (threadIdx.x >= off) ? sm[threadIdx.x - off] : 0;
            __syncthreads();
            sm[threadIdx.x] += t;
            __syncthreads();
        }
        if (i < NN) col_ptr[i] = carry + sm[threadIdx.x] - v;  // exclusive
        __syncthreads();
        if (threadIdx.x == 0) carry += sm[1023];
        __syncthreads();
    }
    if (threadIdx.x == 0) col_ptr[NN] = carry;
}

__global__ void k_scatter(const int* __restrict__ ei, const float* __restrict__ ea,
                          const float* __restrict__ dinv, const int* __restrict__ col_ptr,
                          int* __restrict__ fill, int* __restrict__ csr_src,
                          float* __restrict__ csr_w) {
    int e = blockIdx.x * 256 + threadIdx.x;
    if (e >= NE) return;
    int r = ei[e], c = ei[NE + e];
    float w = dinv[r] * ea[e] * dinv[c];
    int pos = col_ptr[c] + atomicAdd(&fill[c], 1);
    csr_src[pos] = r;
    csr_w[pos] = w;
}

// ---------- dense transform: m = hin @ W ----------
template <int K>
__global__ void k_gemm(const float* __restrict__ hin, const float* __restrict__ W,
                       float* __restrict__ m) {
    __shared__ float hrow[K];
    int rowid = blockIdx.x, t = threadIdx.x;  // block = 128 threads
    if (t < K) hrow[t] = hin[(size_t)rowid * K + t];
    __syncthreads();
    float acc = 0.f;
#pragma unroll
    for (int k = 0; k < K; k++) acc += hrow[k] * W[k * HD + t];
    m[(size_t)rowid * HD + t] = acc;
}

// ---------- sparse aggregation (CSR gather, no atomics) ----------
__global__ void k_agg(const float* __restrict__ m, const int* __restrict__ col_ptr,
                      const int* __restrict__ csr_src, const float* __restrict__ csr_w,
                      const float* __restrict__ dinv, const float* __restrict__ bias,
                      float* __restrict__ hpre) {
    int node = blockIdx.x * 4 + (threadIdx.x >> 6);  // 4 waves/block, 1 node/wave
    if (node >= NN) return;
    int lane = threadIdx.x & 63;
    const float2* m2 = (const float2*)m;  // row stride 64 float2
    float di = dinv[node];
    float2 vs = m2[(size_t)node * 64 + lane];
    float a0 = di * di * vs.x;
    float a1 = di * di * vs.y;
    int beg = col_ptr[node], end = col_ptr[node + 1];
    for (int p = beg; p < end; p++) {
        int s = csr_src[p];
        float w = csr_w[p];
        float2 v = m2[(size_t)s * 64 + lane];
        a0 += w * v.x;
        a1 += w * v.y;
    }
    float2 b = ((const float2*)bias)[lane];
    float2 o;
    o.x = a0 + b.x;
    o.y = a1 + b.y;
    ((float2*)hpre)[(size_t)node * 64 + lane] = o;
}

// ---------- batchnorm stats (sum, sumsq per channel) ----------
__global__ void k_bnstats(const float* __restrict__ hpre, float* __restrict__ stats) {
    int t = threadIdx.x;  // channel, block = 128
    float s = 0.f, s2 = 0.f;
    for (int r = blockIdx.x; r < NN; r += gridDim.x) {
        float v = hpre[(size_t)r * HD + t];
        s += v;
        s2 += v * v;
    }
    atomicAdd(&stats[t], s);
    atomicAdd(&stats[HD + t], s2);
}

// ---------- batchnorm apply + SiLU ----------
__global__ void k_bnapply(const float* __restrict__ hpre, const float* __restrict__ stats,
                          const float* __restrict__ gamma, const float* __restrict__ beta,
                          float* __restrict__ h) {
    int idx = blockIdx.x * 256 + threadIdx.x;
    if (idx >= NN * HD) return;
    int c = idx & (HD - 1);
    const float invn = 1.0f / NN;
    float mu = stats[c] * invn;
    float var = stats[HD + c] * invn - mu * mu;
    float xn = (hpre[idx] - mu) * rsqrtf(var + BN_EPS);
    float y = gamma[c] * xn + beta[c];
    h[idx] = y / (1.f + __expf(-y));  // SiLU
}

// ---------- global mean pool ----------
__global__ void k_pool(const float* __restrict__ h, const int* __restrict__ batch,
                       float* __restrict__ pooled, float* __restrict__ gcount) {
    int r = blockIdx.x * 2 + (threadIdx.x >> 7);  // 2 rows/block of 256
    if (r >= NN) return;
    int c = threadIdx.x & (HD - 1);
    int g = batch[r];
    atomicAdd(&pooled[g * HD + c], h[(size_t)r * HD + c]);
    if (c == 0) atomicAdd(&gcount[g], 1.0f);
}

// ---------- head MLP: silu(pooled@fc1+b) @ fc2 + b -> sigmoid ----------
__global__ void k_head(const float* __restrict__ pooled, const float* __restrict__ gcount,
                       const float* __restrict__ fc1w, const float* __restrict__ fc1b,
                       const float* __restrict__ fc2w, const float* __restrict__ fc2b,
                       float* __restrict__ out) {
    int g = blockIdx.x;
    int j = threadIdx.x;  // 64 threads = 1 wave
    __shared__ float pa[HD];
    float inv = 1.0f / fmaxf(gcount[g], 1.0f);
    pa[j] = pooled[g * HD + j] * inv;
    pa[j + 64] = pooled[g * HD + 64 + j] * inv;
    __syncthreads();
    float a = fc1b[j];
    for (int k = 0; k < HD; k++) a += pa[k] * fc1w[k * 64 + j];
    a = a / (1.f + __expf(-a));  // SiLU
    float v = a * fc2w[j];
    for (int off = 32; off > 0; off >>= 1) v += __shfl_down(v, off);
    if (j == 0) out[g] = 1.f / (1.f + __expf(-(v + fc2b[0])));
}

extern "C" void kernel_launch(void* const* d_in, const int* in_sizes, int n_in,
                              void* d_out, int out_size, void* d_ws, size_t ws_size,
                              hipStream_t stream) {
    const float* x = (const float*)d_in[0];
    const int* ei = (const int*)d_in[1];     // [2, E] row-major: row=ei[0..E), col=ei[E..2E)
    const float* ea = (const float*)d_in[2];
    const int* batch = (const int*)d_in[3];
    // d_in[4] = num_graphs (=64, hardcoded)
    const float* conv0_w = (const float*)d_in[5];
    const float* conv0_b = (const float*)d_in[6];
    const float* conv_ws = (const float*)d_in[7];
    const float* conv_bs = (const float*)d_in[8];
    const float* bn_gamma = (const float*)d_in[9];
    const float* bn_beta = (const float*)d_in[10];
    const float* fc1w = (const float*)d_in[11];
    const float* fc1b = (const float*)d_in[12];
    const float* fc2w = (const float*)d_in[13];
    const float* fc2b = (const float*)d_in[14];
    float* out = (float*)d_out;

    char* ws = (char*)d_ws;
    size_t off = 0;
    auto alloc = [&](size_t bytes) -> char* {
        char* p = ws + off;
        off = (off + bytes + 255) & ~(size_t)255;
        return p;
    };
    float* dinv = (float*)alloc(NN * 4);
    int* cnt = (int*)alloc(NN * 4);
    int* col_ptr = (int*)alloc((NN + 1) * 4);
    int* fill = (int*)alloc(NN * 4);
    int* csr_src = (int*)alloc(NE * 4);
    float* csr_w = (float*)alloc(NE * 4);
    float* mbuf = (float*)alloc((size_t)NN * HD * 4);
    float* hpre = (float*)alloc((size_t)NN * HD * 4);
    float* hbuf = (float*)alloc((size_t)NN * HD * 4);
    float* stats = (float*)alloc(4 * 2 * HD * 4);
    float* pooled = (float*)alloc(NGR * HD * 4);
    float* gcount = (float*)alloc(NGR * 4);

    hipMemsetAsync(cnt, 0, NN * 4, stream);
    hipMemsetAsync(fill, 0, NN * 4, stream);
    hipMemsetAsync(stats, 0, 4 * 2 * HD * 4, stream);
    hipMemsetAsync(pooled, 0, NGR * HD * 4, stream);
    hipMemsetAsync(gcount, 0, NGR * 4, stream);

    k_init_deg<<<(NN + 255) / 256, 256, 0, stream>>>(dinv);
    k_deg_edges<<<(NE + 255) / 256, 256, 0, stream>>>(ei, ea, dinv);
    k_dinv<<<(NN + 255) / 256, 256, 0, stream>>>(dinv);
    k_hist<<<(NE + 255) / 256, 256, 0, stream>>>(ei, cnt);
    k_scan<<<1, 1024, 0, stream>>>(cnt, col_ptr);
    k_scatter<<<(NE + 255) / 256, 256, 0, stream>>>(ei, ea, dinv, col_ptr, fill, csr_src, csr_w);

    for (int L = 0; L < 4; ++L) {
        if (L == 0)
            k_gemm<INF><<<NN, HD, 0, stream>>>(x, conv0_w, mbuf);
        else
            k_gemm<HD><<<NN, HD, 0, stream>>>(hbuf, conv_ws + (size_t)(L - 1) * HD * HD, mbuf);
        const float* bias = (L == 0) ? conv0_b : conv_bs + (L - 1) * HD;
        k_agg<<<(NN + 3) / 4, 256, 0, stream>>>(mbuf, col_ptr, csr_src, csr_w, dinv, bias, hpre);
        float* st = stats + L * 2 * HD;
        k_bnstats<<<512, HD, 0, stream>>>(hpre, st);
        k_bnapply<<<(NN * HD + 255) / 256, 256, 0, stream>>>(hpre, st, bn_gamma + L * HD,
                                                             bn_beta + L * HD, hbuf);
    }

    k_pool<<<(NN + 1) / 2, 256, 0, stream>>>(hbuf, batch, pooled, gcount);
    k_head<<<NGR, 64, 0, stream>>>(pooled, gcount, fc1w, fc1b, fc2w, fc2b, out);
}

// Round 2
// 978.145 us; speedup vs baseline: 1.3755x; 1.3755x over previous
//
#include <hip/hip_runtime.h>

#define NN 50000
#define NE 500000
#define NGR 64
#define HD 128
#define INF 5
#define BN_EPS 1e-5f

// ---------- graph norm ----------
__global__ void k_init_deg(float* deg) {
    int i = blockIdx.x * 256 + threadIdx.x;
    if (i < NN) deg[i] = 1.0f;  // self-loop weight
}

__global__ void k_deg_edges(const int* __restrict__ ei, const float* __restrict__ ea,
                            float* __restrict__ deg) {
    int e = blockIdx.x * 256 + threadIdx.x;
    if (e < NE) atomicAdd(&deg[ei[NE + e]], ea[e]);  // col = ei[1]
}

__global__ void k_dinv(float* deg) {
    int i = blockIdx.x * 256 + threadIdx.x;
    if (i < NN) {
        float d = deg[i];
        deg[i] = d > 0.f ? rsqrtf(d) : 0.f;
    }
}

// ---------- CSR build (by destination/col) ----------
__global__ void k_hist(const int* __restrict__ ei, int* __restrict__ cnt) {
    int e = blockIdx.x * 256 + threadIdx.x;
    if (e < NE) atomicAdd(&cnt[ei[NE + e]], 1);
}

__global__ void k_scan(const int* __restrict__ cnt, int* __restrict__ col_ptr) {
    __shared__ int sm[1024];
    __shared__ int carry;
    if (threadIdx.x == 0) carry = 0;
    __syncthreads();
    for (int base = 0; base < NN; base += 1024) {
        int i = base + threadIdx.x;
        int v = (i < NN) ? cnt[i] : 0;
        sm[threadIdx.x] = v;
        __syncthreads();
        for (int off = 1; off < 1024; off <<= 1) {
            int t = (threadIdx.x >= off) ? sm[threadIdx.x - off] : 0;
            __syncthreads();
            sm[threadIdx.x] += t;
            __syncthreads();
        }
        if (i < NN) col_ptr[i] = carry + sm[threadIdx.x] - v;  // exclusive
        __syncthreads();
        if (threadIdx.x == 0) carry += sm[1023];
        __syncthreads();
    }
    if (threadIdx.x == 0) col_ptr[NN] = carry;
}

__global__ void k_scatter(const int* __restrict__ ei, const float* __restrict__ ea,
                          const float* __restrict__ dinv, const int* __restrict__ col_ptr,
                          int* __restrict__ fill, int* __restrict__ csr_src,
                          float* __restrict__ csr_w) {
    int e = blockIdx.x * 256 + threadIdx.x;
    if (e >= NE) return;
    int r = ei[e], c = ei[NE + e];
    float w = dinv[r] * ea[e] * dinv[c];
    int pos = col_ptr[c] + atomicAdd(&fill[c], 1);
    csr_src[pos] = r;
    csr_w[pos] = w;
}

// ---------- dense transform: m = hin @ W ----------
template <int K>
__global__ void k_gemm(const float* __restrict__ hin, const float* __restrict__ W,
                       float* __restrict__ m) {
    __shared__ float hrow[K];
    int rowid = blockIdx.x, t = threadIdx.x;  // block = 128 threads
    if (t < K) hrow[t] = hin[(size_t)rowid * K + t];
    __syncthreads();
    float acc = 0.f;
#pragma unroll
    for (int k = 0; k < K; k++) acc += hrow[k] * W[k * HD + t];
    m[(size_t)rowid * HD + t] = acc;
}

// ---------- sparse aggregation (CSR gather, no atomics) ----------
__global__ void k_agg(const float* __restrict__ m, const int* __restrict__ col_ptr,
                      const int* __restrict__ csr_src, const float* __restrict__ csr_w,
                      const float* __restrict__ dinv, const float* __restrict__ bias,
                      float* __restrict__ hpre) {
    int node = blockIdx.x * 4 + (threadIdx.x >> 6);  // 4 waves/block, 1 node/wave
    if (node >= NN) return;
    int lane = threadIdx.x & 63;
    const float2* m2 = (const float2*)m;  // row stride 64 float2
    float di = dinv[node];
    float2 vs = m2[(size_t)node * 64 + lane];
    float a0 = di * di * vs.x;
    float a1 = di * di * vs.y;
    int beg = col_ptr[node], end = col_ptr[node + 1];
    for (int p = beg; p < end; p++) {
        int s = csr_src[p];
        float w = csr_w[p];
        float2 v = m2[(size_t)s * 64 + lane];
        a0 += w * v.x;
        a1 += w * v.y;
    }
    float2 b = ((const float2*)bias)[lane];
    float2 o;
    o.x = a0 + b.x;
    o.y = a1 + b.y;
    ((float2*)hpre)[(size_t)node * 64 + lane] = o;
}

// ---------- batchnorm stats (sum, sumsq per channel) ----------
__global__ void k_bnstats(const float* __restrict__ hpre, float* __restrict__ stats) {
    int t = threadIdx.x;  // channel, block = 128
    float s = 0.f, s2 = 0.f;
    for (int r = blockIdx.x; r < NN; r += gridDim.x) {
        float v = hpre[(size_t)r * HD + t];
        s += v;
        s2 += v * v;
    }
    atomicAdd(&stats[t], s);
    atomicAdd(&stats[HD + t], s2);
}

// ---------- batchnorm apply + SiLU ----------
__global__ void k_bnapply(const float* __restrict__ hpre, const float* __restrict__ stats,
                          const float* __restrict__ gamma, const float* __restrict__ beta,
                          float* __restrict__ h) {
    int idx = blockIdx.x * 256 + threadIdx.x;
    if (idx >= NN * HD) return;
    int c = idx & (HD - 1);
    const float invn = 1.0f / NN;
    float mu = stats[c] * invn;
    float var = stats[HD + c] * invn - mu * mu;
    float xn = (hpre[idx] - mu) * rsqrtf(var + BN_EPS);
    float y = gamma[c] * xn + beta[c];
    h[idx] = y / (1.f + __expf(-y));  // SiLU
}

// ---------- graph boundaries (batch is sorted) ----------
__global__ void k_gbounds(const int* __restrict__ batch, int* __restrict__ gstart) {
    int g = threadIdx.x;  // 0..NGR (65 threads needed; launch 128)
    if (g > NGR) return;
    // lower_bound: first i with batch[i] >= g
    int lo = 0, hi = NN;
    while (lo < hi) {
        int mid = (lo + hi) >> 1;
        if (batch[mid] < g) lo = mid + 1;
        else hi = mid;
    }
    gstart[g] = lo;
}

// ---------- global mean pool: one block per graph, no atomics ----------
__global__ void k_pool(const float* __restrict__ h, const int* __restrict__ gstart,
                       float* __restrict__ pooled, float* __restrict__ gcount) {
    int g = blockIdx.x;
    int t = threadIdx.x;          // 512 threads
    int c = t & (HD - 1);         // channel
    int ro = t >> 7;              // row offset 0..3
    int beg = gstart[g], end = gstart[g + 1];
    float acc = 0.f;
    for (int r = beg + ro; r < end; r += 4) acc += h[(size_t)r * HD + c];
    __shared__ float sm[512];
    sm[t] = acc;
    __syncthreads();
    if (t < 256) sm[t] += sm[t + 256];
    __syncthreads();
    if (t < 128) {
        float cnt = (float)(end - beg);
        pooled[g * HD + t] = (sm[t] + sm[t + 128]) / fmaxf(cnt, 1.0f);
        if (t == 0) gcount[g] = cnt;
    }
}

// ---------- head MLP: silu(pooled@fc1+b) @ fc2 + b -> sigmoid ----------
__global__ void k_head(const float* __restrict__ pooled, const float* __restrict__ gcount,
                       const float* __restrict__ fc1w, const float* __restrict__ fc1b,
                       const float* __restrict__ fc2w, const float* __restrict__ fc2b,
                       float* __restrict__ out) {
    int g = blockIdx.x;
    int j = threadIdx.x;  // 64 threads = 1 wave
    __shared__ float pa[HD];
    pa[j] = pooled[g * HD + j];
    pa[j + 64] = pooled[g * HD + 64 + j];
    __syncthreads();
    float a = fc1b[j];
    for (int k = 0; k < HD; k++) a += pa[k] * fc1w[k * 64 + j];
    a = a / (1.f + __expf(-a));  // SiLU
    float v = a * fc2w[j];
    for (int off = 32; off > 0; off >>= 1) v += __shfl_down(v, off);
    if (j == 0) out[g] = 1.f / (1.f + __expf(-(v + fc2b[0])));
}

extern "C" void kernel_launch(void* const* d_in, const int* in_sizes, int n_in,
                              void* d_out, int out_size, void* d_ws, size_t ws_size,
                              hipStream_t stream) {
    const float* x = (const float*)d_in[0];
    const int* ei = (const int*)d_in[1];     // [2, E]: row=ei[0..E), col=ei[E..2E)
    const float* ea = (const float*)d_in[2];
    const int* batch = (const int*)d_in[3];
    // d_in[4] = num_graphs (=64, hardcoded)
    const float* conv0_w = (const float*)d_in[5];
    const float* conv0_b = (const float*)d_in[6];
    const float* conv_ws = (const float*)d_in[7];
    const float* conv_bs = (const float*)d_in[8];
    const float* bn_gamma = (const float*)d_in[9];
    const float* bn_beta = (const float*)d_in[10];
    const float* fc1w = (const float*)d_in[11];
    const float* fc1b = (const float*)d_in[12];
    const float* fc2w = (const float*)d_in[13];
    const float* fc2b = (const float*)d_in[14];
    float* out = (float*)d_out;

    char* ws = (char*)d_ws;
    size_t off = 0;
    auto alloc = [&](size_t bytes) -> char* {
        char* p = ws + off;
        off = (off + bytes + 255) & ~(size_t)255;
        return p;
    };
    float* dinv = (float*)alloc(NN * 4);
    int* cnt = (int*)alloc(NN * 4);
    int* col_ptr = (int*)alloc((NN + 1) * 4);
    int* fill = (int*)alloc(NN * 4);
    int* csr_src = (int*)alloc(NE * 4);
    float* csr_w = (float*)alloc(NE * 4);
    float* mbuf = (float*)alloc((size_t)NN * HD * 4);
    float* hpre = (float*)alloc((size_t)NN * HD * 4);
    float* hbuf = (float*)alloc((size_t)NN * HD * 4);
    float* stats = (float*)alloc(4 * 2 * HD * 4);
    float* pooled = (float*)alloc(NGR * HD * 4);
    float* gcount = (float*)alloc(NGR * 4);
    int* gstart = (int*)alloc((NGR + 1) * 4);

    hipMemsetAsync(cnt, 0, NN * 4, stream);
    hipMemsetAsync(fill, 0, NN * 4, stream);
    hipMemsetAsync(stats, 0, 4 * 2 * HD * 4, stream);

    k_init_deg<<<(NN + 255) / 256, 256, 0, stream>>>(dinv);
    k_deg_edges<<<(NE + 255) / 256, 256, 0, stream>>>(ei, ea, dinv);
    k_dinv<<<(NN + 255) / 256, 256, 0, stream>>>(dinv);
    k_hist<<<(NE + 255) / 256, 256, 0, stream>>>(ei, cnt);
    k_scan<<<1, 1024, 0, stream>>>(cnt, col_ptr);
    k_scatter<<<(NE + 255) / 256, 256, 0, stream>>>(ei, ea, dinv, col_ptr, fill, csr_src, csr_w);
    k_gbounds<<<1, 128, 0, stream>>>(batch, gstart);

    for (int L = 0; L < 4; ++L) {
        if (L == 0)
            k_gemm<INF><<<NN, HD, 0, stream>>>(x, conv0_w, mbuf);
        else
            k_gemm<HD><<<NN, HD, 0, stream>>>(hbuf, conv_ws + (size_t)(L - 1) * HD * HD, mbuf);
        const float* bias = (L == 0) ? conv0_b : conv_bs + (L - 1) * HD;
        k_agg<<<(NN + 3) / 4, 256, 0, stream>>>(mbuf, col_ptr, csr_src, csr_w, dinv, bias, hpre);
        float* st = stats + L * 2 * HD;
        k_bnstats<<<512, HD, 0, stream>>>(hpre, st);
        k_bnapply<<<(NN * HD + 255) / 256, 256, 0, stream>>>(hpre, st, bn_gamma + L * HD,
                                                             bn_beta + L * HD, hbuf);
    }

    k_pool<<<NGR, 512, 0, stream>>>(hbuf, gstart, pooled, gcount);
    k_head<<<NGR, 64, 0, stream>>>(pooled, gcount, fc1w, fc1b, fc2w, fc2b, out);
}